// Round 5
// baseline (205.397 us; speedup 1.0000x reference)
//
#include <hip/hip_runtime.h>
#include <cstdint>
#include <cstddef>

typedef unsigned int u32;
typedef unsigned long long u64;

#define NTOT 122740      // total proposals per batch
#define NPAIR 61370      // NTOT/2 proposal pairs per batch
#define KTOP 1024        // top-K kept per batch (deterministic bin-cutoff set)
#define WIN  256         // IoU-matrix window over the sorted list
#define NBIN 4096
#define SCORE_T 0.25f
#define TBITS 0x3E800000u       // bit pattern of 0.25f
#define HSPLIT_BITS 0x3EFFF000u // bits threshold <=> score_bin >= 2048 (score ~0.5)
#define CSTRIDE 64              // counter padding (u32s)
#define CAP 30685               // per-batch per-class candidate capacity

// level layout: [offset, count) per pyramid level (batch strides in floats: N*6)
// L2: [0,      92416)  152x152 s4   N=92416
// L3: [92416,  115520) 76x76   s8   N=23104
// L4: [115520, 121296) 38x38   s16  N=5776
// L5: [121296, 122740) 19x19   s32  N=1444

// ws layout (bytes):
//   hist:     32*4096*4 = 524288    @ 0
//   counters: 32*64*4   = 8192      @ 524288   ([0]=nH, [1]=nL per batch)
//   candH:    32*CAP*8  = 7855360   @ 532480
//   candL:    32*CAP*8  = 7855360   @ 8387840
//   total 16.2 MB
#define WS_COUNTERS 524288
#define WS_CANDH    532480
#define WS_CANDL    8387840

// ---------------------------------------------------------------- helpers
__device__ __forceinline__ float sigm(float x) { return 1.0f / (1.0f + expf(-x)); }

// valid scores [0.25,1) -> bins 1..4095 (monotone in bits); 0 = invalid
__device__ __forceinline__ int score_bin(u32 bits) {
  return min(4095, 1 + (int)((bits - TBITS) >> 12));
}

__device__ __forceinline__ u64 shfl_u64(u64 x, int src) {
  int lo = __shfl((int)(u32)x, src, 64);
  int hi = __shfl((int)(u32)(x >> 32), src, 64);
  return ((u64)(u32)hi << 32) | (u32)lo;
}

// wave-aggregated list append: one global atomic per wave, coalesced writes
__device__ __forceinline__ void wave_append(bool pred, u32 bits, u32 gidx,
                                            u32* gcnt, uint2* glist, int lane)
{
  u64 m = __ballot(pred);
  if (!m) return;                     // wave-uniform
  int leader = (int)__ffsll(m) - 1;
  u32 cnt = (u32)__popcll(m);
  u32 base = 0;
  if (lane == leader) base = atomicAdd(gcnt, cnt);
  base = (u32)__shfl((int)base, leader, 64);
  if (pred) {
    u32 pos = base + (u32)__popcll(m & ((1ull << lane) - 1ull));
    if (pos < (u32)CAP) glist[pos] = make_uint2(bits, gidx);
  }
}

__device__ float4 decode_box_from_gidx(u32 gidx, int b,
    const float* __restrict__ p2, const float* __restrict__ p3,
    const float* __restrict__ p4, const float* __restrict__ p5)
{
  const float* p; int t, H, W; float stride;
  float aw0, ah0, aw1, ah1, aw2, ah2, aw3, ah3;
  if (gidx < 92416u) {
    p = p2 + (size_t)b * 92416 * 6; t = (int)gidx; H = 152; W = 152; stride = 4.0f;
    aw0=12.f; ah0=16.f; aw1=19.f; ah1=36.f; aw2=40.f; ah2=28.f; aw3=36.f; ah3=75.f;
  } else if (gidx < 115520u) {
    p = p3 + (size_t)b * 23104 * 6; t = (int)(gidx - 92416u); H = 76; W = 76; stride = 8.0f;
    aw0=36.f; ah0=75.f; aw1=76.f; ah1=55.f; aw2=72.f; ah2=146.f; aw3=142.f; ah3=110.f;
  } else if (gidx < 121296u) {
    p = p4 + (size_t)b * 5776 * 6; t = (int)(gidx - 115520u); H = 38; W = 38; stride = 16.0f;
    aw0=72.f; ah0=146.f; aw1=142.f; ah1=110.f; aw2=192.f; ah2=243.f; aw3=459.f; ah3=401.f;
  } else {
    p = p5 + (size_t)b * 1444 * 6; t = (int)(gidx - 121296u); H = 19; W = 19; stride = 32.0f;
    aw0=142.f; ah0=110.f; aw1=192.f; ah1=243.f; aw2=300.f; ah2=300.f; aw3=459.f; ah3=401.f;
  }
  int HW = H * W;
  int a = t / HW;
  int r = t - a * HW;
  int y = r / W;
  int x = r - y * W;
  const float* q = p + (size_t)t * 6;
  float2 t01 = *(const float2*)(q + 0);
  float2 t23 = *(const float2*)(q + 2);
  float cx = (sigm(t01.x) + (float)x) * stride;
  float cy = (sigm(t01.y) + (float)y) * stride;
  float aw = (a == 0) ? aw0 : (a == 1) ? aw1 : (a == 2) ? aw2 : aw3;
  float ah = (a == 0) ? ah0 : (a == 1) ? ah1 : (a == 2) ? ah2 : ah3;
  float bw = expf(t23.x) * aw;
  float bh = expf(t23.y) * ah;
  return make_float4(cx - 0.5f * bw, cy - 0.5f * bh, cx + 0.5f * bw, cy + 0.5f * bh);
}

__device__ __forceinline__ bool iou_gt(float4 A, float4 B) {
  float ltx = fmaxf(A.x, B.x), lty = fmaxf(A.y, B.y);
  float rbx = fminf(A.z, B.z), rby = fminf(A.w, B.w);
  float w = fmaxf(rbx - ltx, 0.0f), h = fmaxf(rby - lty, 0.0f);
  float inter = w * h;
  float a1 = fmaxf(A.z - A.x, 0.0f) * fmaxf(A.w - A.y, 0.0f);
  float a2 = fmaxf(B.z - B.x, 0.0f) * fmaxf(B.w - B.y, 0.0f);
  float iou = inter / (a1 + a2 - inter + 1e-9f);
  return iou > 0.5f;
}

// ---------------------------------------------------------------- A: decode scores + hist + candidate append
// 30x32 blocks, 256 thr. Loads ONLY conf/cls (16 B per 48 B pair). Survivors
// (score >= 0.25) are appended to per-batch H (score>=~0.5) / L lists via
// wave-aggregated global atomics. No full scores array round-trip.
__global__ __launch_bounds__(256)
void decode_score_hist(const float* __restrict__ p2, const float* __restrict__ p3,
                       const float* __restrict__ p4, const float* __restrict__ p5,
                       u32* __restrict__ hist, u32* __restrict__ counters,
                       uint2* __restrict__ candH, uint2* __restrict__ candL)
{
  __shared__ u32 lhist[NBIN];
  const int tid = threadIdx.x;
  const int lane = tid & 63;
  const int b = blockIdx.y;
  for (int i = tid; i < NBIN; i += 256) lhist[i] = 0u;
  __syncthreads();

  u32* gcH = counters + (size_t)b * CSTRIDE;
  u32* gcL = gcH + 1;
  uint2* gH = candH + (size_t)b * CAP;
  uint2* gL = candL + (size_t)b * CAP;

  const int pbase = blockIdx.x * 2048;
  for (int k = 0; k < 8; ++k) {
    int P = pbase + k * 256 + tid;
    u32 b0 = 0, b1 = 0, gi0 = 0, gi1 = 0;
    if (P < NPAIR) {
      int t0 = 2 * P;
      const float* p; int l0, LN;
      if (t0 < 92416)       { p = p2; l0 = t0;          LN = 92416; }
      else if (t0 < 115520) { p = p3; l0 = t0 - 92416;  LN = 23104; }
      else if (t0 < 121296) { p = p4; l0 = t0 - 115520; LN = 5776;  }
      else                  { p = p5; l0 = t0 - 121296; LN = 1444;  }
      const float* q = p + ((size_t)b * LN + (size_t)l0) * 6;
      float2 c0 = *(const float2*)(q + 4);    // conf0, cls0  (16-aligned)
      float2 c1 = *(const float2*)(q + 10);   // conf1, cls1  (8-aligned)
      float s0 = sigm(c0.x) * sigm(c0.y);
      float s1 = sigm(c1.x) * sigm(c1.y);
      b0 = (s0 >= SCORE_T) ? __float_as_uint(s0) : 0u;
      b1 = (s1 >= SCORE_T) ? __float_as_uint(s1) : 0u;
      gi0 = (u32)t0; gi1 = (u32)(t0 + 1);
      if (b0) atomicAdd(&lhist[score_bin(b0)], 1u);
      if (b1) atomicAdd(&lhist[score_bin(b1)], 1u);
    }
    wave_append(b0 != 0u && b0 >= HSPLIT_BITS, b0, gi0, gcH, gH, lane);
    wave_append(b0 != 0u && b0 <  HSPLIT_BITS, b0, gi0, gcL, gL, lane);
    wave_append(b1 != 0u && b1 >= HSPLIT_BITS, b1, gi1, gcH, gH, lane);
    wave_append(b1 != 0u && b1 <  HSPLIT_BITS, b1, gi1, gcL, gL, lane);
  }
  __syncthreads();
  u32* gh = hist + (size_t)b * NBIN;
  for (int i = tid; i < NBIN; i += 256) {
    u32 v = lhist[i];
    if (v) atomicAdd(&gh[i], v);
  }
}

// ---------------------------------------------------------------- M: fused scan+filter+sort+NMS
// One block per batch. Phases:
//  1. wave 0: barrier-free shfl suffix-scan of hist -> B, n, bin starts
//     (waves 1..15 zero skey/skey2 in parallel)
//  2. scatter candidates (H list; L only if B<2048) into LDS counting slots
//  3. exact in-bin rank sort (barrier-free)
//  4. decode window boxes, IoU bitmask matrix (conflict-free mapping)
//  5. register-resident greedy NMS on wave 0, exact slow path, output
__global__ __launch_bounds__(1024, 1)
void mega_kernel(const u32* __restrict__ hist, const u32* __restrict__ counters,
                 const uint2* __restrict__ candH, const uint2* __restrict__ candL,
                 const float* __restrict__ p2, const float* __restrict__ p3,
                 const float* __restrict__ p4, const float* __restrict__ p5,
                 float* __restrict__ out)
{
  const int b = blockIdx.x;
  const int tid = threadIdx.x;

  __shared__ u32 sstart[NBIN];      // 16 KB  bin start slot = cnt_ge(bin+1)
  __shared__ u32 scur[NBIN];        // 16 KB  cursors (scratch for phase-1 reduce)
  __shared__ u64 skey[KTOP];        // 8 KB   scattered (bin-grouped) keys
  __shared__ u64 skey2[KTOP];       // 8 KB   exactly sorted keys
  __shared__ float4 sbox[WIN];      // 4 KB
  __shared__ u64 smat[WIN * 4];     // 8 KB   [word][row]
  __shared__ float4 selbox[100];    // 1.6 KB
  __shared__ int s_misc[4];         // [2]=n_sel, [3]=need slow
  __shared__ int s_B, s_n;

  // ---- phase 1: wave-0 shfl suffix scan; others zero key arrays
  if (tid < 64) {
    const uint4* gq = (const uint4*)(hist + (size_t)b * NBIN + (size_t)tid * 64);
    u32 h[64];
    #pragma unroll
    for (int i = 0; i < 16; ++i) {
      uint4 t = gq[i];
      h[4*i] = t.x; h[4*i+1] = t.y; h[4*i+2] = t.z; h[4*i+3] = t.w;
    }
    u32 lsum = 0;
    #pragma unroll
    for (int k = 0; k < 64; ++k) lsum += h[k];
    u32 S = lsum;                               // will become cnt_ge(64*tid)
    #pragma unroll
    for (int off = 1; off < 64; off <<= 1) {
      u32 v = (u32)__shfl_down((int)S, off, 64);
      if (tid + off < 64) S += v;
    }
    u32 c = S - lsum;                           // cnt_ge(64*tid + 64)
    int Bv = -1; u32 nv = 0;
    for (int k = 63; k >= 0; --k) {
      sstart[tid * 64 + k] = c;                 // cnt_ge(bin+1)
      c += h[k];                                // c = cnt_ge(bin)
      if (c <= (u32)KTOP) { Bv = tid * 64 + k; nv = c; }
    }
    scur[tid]      = (Bv < 0) ? 0xFFFFFFFFu : (u32)Bv;   // scratch
    scur[64 + tid] = nv;
  } else {
    for (int i = tid - 64; i < KTOP; i += 960) { skey[i] = 0ull; skey2[i] = 0ull; }
  }
  __syncthreads();
  if (tid == 0) {
    u32 bb = 0xFFFFFFFFu, nn = 0;
    for (int l = 0; l < 64; ++l) {
      u32 v = scur[l];
      if (v < bb) { bb = v; nn = scur[64 + l]; }
    }
    if (bb == 0xFFFFFFFFu) { s_B = 4095; s_n = KTOP; }   // statistically unreachable
    else { s_B = max((int)bb, 1); s_n = (int)nn; }
  }
  __syncthreads();
  const int B = s_B;
  const int n = min(s_n, KTOP);

  // ---- init cursors
  for (int i = tid; i < NBIN; i += 1024) scur[i] = sstart[i];
  __syncthreads();

  // ---- phase 2: scatter candidates into LDS counting slots
  {
    const int nH = min((int)counters[(size_t)b * CSTRIDE], CAP);
    const uint2* src = candH + (size_t)b * CAP;
    for (int i = tid; i < nH; i += 1024) {
      uint2 e = src[i];
      int bin = score_bin(e.x);
      if (bin >= B) {
        u32 slot = atomicAdd(&scur[bin], 1u);
        if (slot < (u32)KTOP) skey[slot] = ((u64)e.x << 32) | (u32)(~e.y);
      }
    }
  }
  if (B < 2048) {     // kept set reaches below the H/L split: read L too
    const int nL = min((int)counters[(size_t)b * CSTRIDE + 1], CAP);
    const uint2* src = candL + (size_t)b * CAP;
    for (int i = tid; i < nL; i += 1024) {
      uint2 e = src[i];
      int bin = score_bin(e.x);
      if (bin >= B) {
        u32 slot = atomicAdd(&scur[bin], 1u);
        if (slot < (u32)KTOP) skey[slot] = ((u64)e.x << 32) | (u32)(~e.y);
      }
    }
  }
  __syncthreads();

  // ---- phase 3: exact rank sort within bins (barrier-free)
  // final slot = sstart[bin] + |{bin-mates with strictly greater key}|; keys distinct
  for (int s = tid; s < n; s += 1024) {
    u64 k = skey[s];
    int bin = score_bin((u32)(k >> 32));
    int st = (int)sstart[bin];
    int en = (int)scur[bin];
    u32 r = 0;
    for (int j = st; j < en; ++j) r += (skey[j] > k) ? 1u : 0u;
    skey2[st + r] = k;
  }
  __syncthreads();

  const int Wn = min(n, WIN);

  // ---- phase 4a: decode boxes for the window
  if (tid < WIN) {
    sbox[tid] = (tid < Wn) ? decode_box_from_gidx(~(u32)skey2[tid], b, p2, p3, p4, p5)
                           : make_float4(0.f, 0.f, 0.f, 0.f);
  }
  __syncthreads();

  // ---- phase 4b: IoU bitmask matrix; row = tid&255, word = tid>>8 (broadcast reads)
  {
    int row = tid & 255, word = tid >> 8;
    u64 bits = 0;
    if (row < Wn) {
      float4 A = sbox[row];
      int j0 = word * 64;
      int je = min(64, Wn - j0);
      for (int j = 0; j < je; ++j)
        if (iou_gt(A, sbox[j0 + j])) bits |= (1ull << j);
    }
    smat[word * 256 + row] = bits;
  }
  __syncthreads();

  // ---- phase 5: greedy selection on wave 0, matrix rows in registers
  if (tid < 64) {
    const int lane = tid;
    u64 m0[4], m1[4], m2[4], m3[4];
    #pragma unroll
    for (int w = 0; w < 4; ++w) {
      m0[w] = smat[w * 256 +   0 + lane];
      m1[w] = smat[w * 256 +  64 + lane];
      m2[w] = smat[w * 256 + 128 + lane];
      m3[w] = smat[w * 256 + 192 + lane];
    }
    u64 live[4];
    #pragma unroll
    for (int g2 = 0; g2 < 4; ++g2) {
      int lo = g2 * 64;
      live[g2] = (Wn >= lo + 64) ? ~0ull : (Wn > lo ? ((1ull << (Wn - lo)) - 1ull) : 0ull);
    }
    int sel = 0;
    #pragma unroll 1
    for (int w2 = 0; w2 < 4; ++w2) {
      while (live[w2] && sel < 100) {
        int j = (int)__ffsll(live[w2]) - 1;
        int p = (w2 << 6) + j;
        u64 r0, r1, r2, r3;
        if (w2 == 0)      { r0 = shfl_u64(m0[0], j); r1 = shfl_u64(m0[1], j); r2 = shfl_u64(m0[2], j); r3 = shfl_u64(m0[3], j); }
        else if (w2 == 1) { r0 = shfl_u64(m1[0], j); r1 = shfl_u64(m1[1], j); r2 = shfl_u64(m1[2], j); r3 = shfl_u64(m1[3], j); }
        else if (w2 == 2) { r0 = shfl_u64(m2[0], j); r1 = shfl_u64(m2[1], j); r2 = shfl_u64(m2[2], j); r3 = shfl_u64(m2[3], j); }
        else              { r0 = shfl_u64(m3[0], j); r1 = shfl_u64(m3[1], j); r2 = shfl_u64(m3[2], j); r3 = shfl_u64(m3[3], j); }
        live[0] &= ~r0; live[1] &= ~r1; live[2] &= ~r2; live[3] &= ~r3;
        live[w2] &= ~(1ull << j);     // self-bit (IoU(self)=1 sets it anyway)
        if (lane == 0) {
          float4 box = sbox[p];
          u64 k = skey2[p];
          float sc = __uint_as_float((u32)(k >> 32));
          selbox[sel] = box;
          float* orow = out + (size_t)b * 500 + (size_t)sel * 5;
          orow[0] = box.x; orow[1] = box.y; orow[2] = box.z; orow[3] = box.w; orow[4] = sc;
        }
        sel++;
      }
    }
    if (lane == 0) {
      s_misc[2] = sel;
      s_misc[3] = (sel < 100 && n > WIN) ? 1 : 0;
    }
  }
  __syncthreads();

  // ---- exact slow path beyond the window (statistically never taken)
  if (s_misc[3]) {
    if (tid < 64) {
      const int lane = tid;
      int sel = s_misc[2];
      for (int p = WIN; p < n && sel < 100; ++p) {
        u64 k = skey2[p];
        float4 box = decode_box_from_gidx(~(u32)k, b, p2, p3, p4, p5);
        bool hit = false;
        if (lane < sel) hit = iou_gt(selbox[lane], box);
        if (lane + 64 < sel) hit = hit || iou_gt(selbox[lane + 64], box);
        u64 anyhit = __ballot(hit);
        if (anyhit == 0ull) {
          if (lane == 0) {
            selbox[sel] = box;
            float sc = __uint_as_float((u32)(k >> 32));
            float* orow = out + (size_t)b * 500 + (size_t)sel * 5;
            orow[0] = box.x; orow[1] = box.y; orow[2] = box.z; orow[3] = box.w; orow[4] = sc;
          }
          sel++;
        }
      }
      if (lane == 0) s_misc[2] = sel;
    }
  }
  __syncthreads();

  // ---- zero-fill remaining rows
  const int nsel = s_misc[2];
  for (int i = tid; i < (100 - nsel) * 5; i += 1024)
    out[(size_t)b * 500 + (size_t)nsel * 5 + i] = 0.0f;
}

// ---------------------------------------------------------------- launch
extern "C" void kernel_launch(void* const* d_in, const int* in_sizes, int n_in,
                              void* d_out, int out_size, void* d_ws, size_t ws_size,
                              hipStream_t stream) {
  const float* p2 = (const float*)d_in[0];
  const float* p3 = (const float*)d_in[1];
  const float* p4 = (const float*)d_in[2];
  const float* p5 = (const float*)d_in[3];
  float* out = (float*)d_out;

  unsigned char* w = (unsigned char*)d_ws;
  u32*   hist     = (u32*)w;
  u32*   counters = (u32*)(w + WS_COUNTERS);
  uint2* candH    = (uint2*)(w + WS_CANDH);
  uint2* candL    = (uint2*)(w + WS_CANDL);

  hipMemsetAsync(w, 0, WS_CANDH, stream);   // hist + counters
  decode_score_hist<<<dim3(30, 32), 256, 0, stream>>>(p2, p3, p4, p5,
                                                      hist, counters, candH, candL);
  mega_kernel<<<32, 1024, 0, stream>>>(hist, counters, candH, candL,
                                       p2, p3, p4, p5, out);
}

// Round 6
// 171.006 us; speedup vs baseline: 1.2011x; 1.2011x over previous
//
#include <hip/hip_runtime.h>
#include <cstdint>
#include <cstddef>

typedef unsigned int u32;
typedef unsigned long long u64;

#define NTOT 122740      // total proposals per batch
#define NPAIR 61370      // NTOT/2 proposal pairs per batch
#define KTOP 1024        // top-K kept per batch (deterministic bin-cutoff set)
#define WIN  256         // IoU-matrix window over the sorted list
#define NBIN 4096
#define SCORE_T 0.25f
#define TBITS 0x3E800000u       // bit pattern of 0.25f
#define HSPLIT_BITS 0x3EFFF000u // bits >= this  <=>  score_bin >= 2048 (score ~0.5)
#define CSTRIDE 64              // counter padding (u32s)
#define CAP_H 40960             // per-batch H-list capacity (nH ~14k typical)
#define CAP_L 20480             // per-batch L-list capacity (only read if nH < KTOP)

// level layout: [offset, count) per pyramid level (batch strides in floats: N*6)
// L2: [0,      92416)  152x152 s4   N=92416
// L3: [92416,  115520) 76x76   s8   N=23104
// L4: [115520, 121296) 38x38   s16  N=5776
// L5: [121296, 122740) 19x19   s32  N=1444

// ws layout (bytes):
//   counters: 32*64*4        = 8192      @ 0   ([0]=nH true count, [1]=nL true count)
//   candH:    32*CAP_H*8     = 10485760  @ 8192
//   candL:    32*CAP_L*8     = 5242880   @ 10493952
//   total 15.7 MB
#define WS_CANDH 8192
#define WS_CANDL 10493952

// ---------------------------------------------------------------- helpers
__device__ __forceinline__ float sigm(float x) { return 1.0f / (1.0f + expf(-x)); }

// valid scores [0.25,1) -> bins 1..4095 (monotone in bits); 0 = invalid
__device__ __forceinline__ int score_bin(u32 bits) {
  return min(4095, 1 + (int)((bits - TBITS) >> 12));
}

__device__ __forceinline__ u64 shfl_u64(u64 x, int src) {
  int lo = __shfl((int)(u32)x, src, 64);
  int hi = __shfl((int)(u32)(x >> 32), src, 64);
  return ((u64)(u32)hi << 32) | (u32)lo;
}

// scores for proposal pair P (props 2P, 2P+1) of batch b.
// loads exactly two 16B-aligned float4: (conf0,cls0,t1x,t1y) and (tw1,th1,conf1,cls1)
__device__ __forceinline__ void score_pair(int P, int b,
    const float* __restrict__ p2, const float* __restrict__ p3,
    const float* __restrict__ p4, const float* __restrict__ p5,
    u32& b0, u32& b1, u32& gi0, u32& gi1)
{
  int t0 = 2 * P;
  const float* p; int l0, LN;
  if (t0 < 92416)       { p = p2; l0 = t0;          LN = 92416; }
  else if (t0 < 115520) { p = p3; l0 = t0 - 92416;  LN = 23104; }
  else if (t0 < 121296) { p = p4; l0 = t0 - 115520; LN = 5776;  }
  else                  { p = p5; l0 = t0 - 121296; LN = 1444;  }
  const float* q = p + ((size_t)b * LN + (size_t)l0) * 6;
  float4 v1 = *(const float4*)(q + 4);   // conf0, cls0, t1x, t1y
  float4 v2 = *(const float4*)(q + 8);   // tw1, th1, conf1, cls1
  float s0 = sigm(v1.x) * sigm(v1.y);
  float s1 = sigm(v2.z) * sigm(v2.w);
  b0 = (s0 >= SCORE_T) ? __float_as_uint(s0) : 0u;
  b1 = (s1 >= SCORE_T) ? __float_as_uint(s1) : 0u;
  gi0 = (u32)t0; gi1 = (u32)(t0 + 1);
}

__device__ float4 decode_box_from_gidx(u32 gidx, int b,
    const float* __restrict__ p2, const float* __restrict__ p3,
    const float* __restrict__ p4, const float* __restrict__ p5)
{
  const float* p; int t, H, W; float stride;
  float aw0, ah0, aw1, ah1, aw2, ah2, aw3, ah3;
  if (gidx < 92416u) {
    p = p2 + (size_t)b * 92416 * 6; t = (int)gidx; H = 152; W = 152; stride = 4.0f;
    aw0=12.f; ah0=16.f; aw1=19.f; ah1=36.f; aw2=40.f; ah2=28.f; aw3=36.f; ah3=75.f;
  } else if (gidx < 115520u) {
    p = p3 + (size_t)b * 23104 * 6; t = (int)(gidx - 92416u); H = 76; W = 76; stride = 8.0f;
    aw0=36.f; ah0=75.f; aw1=76.f; ah1=55.f; aw2=72.f; ah2=146.f; aw3=142.f; ah3=110.f;
  } else if (gidx < 121296u) {
    p = p4 + (size_t)b * 5776 * 6; t = (int)(gidx - 115520u); H = 38; W = 38; stride = 16.0f;
    aw0=72.f; ah0=146.f; aw1=142.f; ah1=110.f; aw2=192.f; ah2=243.f; aw3=459.f; ah3=401.f;
  } else {
    p = p5 + (size_t)b * 1444 * 6; t = (int)(gidx - 121296u); H = 19; W = 19; stride = 32.0f;
    aw0=142.f; ah0=110.f; aw1=192.f; ah1=243.f; aw2=300.f; ah2=300.f; aw3=459.f; ah3=401.f;
  }
  int HW = H * W;
  int a = t / HW;
  int r = t - a * HW;
  int y = r / W;
  int x = r - y * W;
  const float* q = p + (size_t)t * 6;
  float2 t01 = *(const float2*)(q + 0);
  float2 t23 = *(const float2*)(q + 2);
  float cx = (sigm(t01.x) + (float)x) * stride;
  float cy = (sigm(t01.y) + (float)y) * stride;
  float aw = (a == 0) ? aw0 : (a == 1) ? aw1 : (a == 2) ? aw2 : aw3;
  float ah = (a == 0) ? ah0 : (a == 1) ? ah1 : (a == 2) ? ah2 : ah3;
  float bw = expf(t23.x) * aw;
  float bh = expf(t23.y) * ah;
  return make_float4(cx - 0.5f * bw, cy - 0.5f * bh, cx + 0.5f * bw, cy + 0.5f * bh);
}

__device__ __forceinline__ bool iou_gt(float4 A, float4 B) {
  float ltx = fmaxf(A.x, B.x), lty = fmaxf(A.y, B.y);
  float rbx = fminf(A.z, B.z), rby = fminf(A.w, B.w);
  float w = fmaxf(rbx - ltx, 0.0f), h = fmaxf(rby - lty, 0.0f);
  float inter = w * h;
  float a1 = fmaxf(A.z - A.x, 0.0f) * fmaxf(A.w - A.y, 0.0f);
  float a2 = fmaxf(B.z - B.x, 0.0f) * fmaxf(B.w - B.y, 0.0f);
  float iou = inter / (a1 + a2 - inter + 1e-9f);
  return iou > 0.5f;
}

// ---------------------------------------------------------------- A: decode + classify + append
// 120x32 blocks, 256 thr, 512 pairs/block. Pure streaming: dual-float4 loads,
// no histogram. Survivors staged in LDS (cannot overflow: 1024 props/block max
// per class), flushed with ONE global atomic per class per block. Counters
// accumulate TRUE totals even if a list cap truncates (mega guards on them).
__global__ __launch_bounds__(256)
void decode_kernel(const float* __restrict__ p2, const float* __restrict__ p3,
                   const float* __restrict__ p4, const float* __restrict__ p5,
                   u32* __restrict__ counters,
                   uint2* __restrict__ candH, uint2* __restrict__ candL)
{
  __shared__ uint2 stH[1024];
  __shared__ uint2 stL[1024];
  __shared__ u32 s_cH, s_cL, s_bH, s_bL;
  const int tid = threadIdx.x;
  const int b = blockIdx.y;
  if (tid == 0) { s_cH = 0u; s_cL = 0u; }
  __syncthreads();

  const int pbase = blockIdx.x * 512;
  #pragma unroll
  for (int k = 0; k < 2; ++k) {
    int P = pbase + k * 256 + tid;
    if (P < NPAIR) {
      u32 b0, b1, gi0, gi1;
      score_pair(P, b, p2, p3, p4, p5, b0, b1, gi0, gi1);
      if (b0) {
        bool H = (b0 >= HSPLIT_BITS);
        u32 pos = atomicAdd(H ? &s_cH : &s_cL, 1u);
        (H ? stH : stL)[pos] = make_uint2(b0, gi0);
      }
      if (b1) {
        bool H = (b1 >= HSPLIT_BITS);
        u32 pos = atomicAdd(H ? &s_cH : &s_cL, 1u);
        (H ? stH : stL)[pos] = make_uint2(b1, gi1);
      }
    }
  }
  __syncthreads();
  if (tid == 0) {
    if (s_cH) s_bH = atomicAdd(&counters[(size_t)b * CSTRIDE],     s_cH);
    if (s_cL) s_bL = atomicAdd(&counters[(size_t)b * CSTRIDE + 1], s_cL);
  }
  __syncthreads();
  uint2* gH = candH + (size_t)b * CAP_H;
  uint2* gL = candL + (size_t)b * CAP_L;
  const u32 mH = s_cH, mL = s_cL;
  for (u32 i = tid; i < mH; i += 256) { u32 d = s_bH + i; if (d < (u32)CAP_H) gH[d] = stH[i]; }
  for (u32 i = tid; i < mL; i += 256) { u32 d = s_bL + i; if (d < (u32)CAP_L) gL[d] = stL[i]; }
}

// ---------------------------------------------------------------- M: fused hist+scan+sort+NMS
// One block per batch. L list read ONLY if nH < KTOP (then the keep-set may dip
// below the split; otherwise H-only hist provably yields the exact keep-set).
// If a needed list overflowed its cap -> exact raw-rescan fallback (never taken).
__global__ __launch_bounds__(1024, 1)
void mega_kernel(const u32* __restrict__ counters,
                 const uint2* __restrict__ candH, const uint2* __restrict__ candL,
                 const float* __restrict__ p2, const float* __restrict__ p3,
                 const float* __restrict__ p4, const float* __restrict__ p5,
                 float* __restrict__ out)
{
  const int b = blockIdx.x;
  const int tid = threadIdx.x;

  __shared__ u32 sstart[NBIN];      // 16 KB  cnt_ge(bin+1) = bin start slot
  __shared__ u32 scur[NBIN];        // 16 KB  hist, then cursors
  __shared__ u64 skey[KTOP];        // 8 KB   bin-grouped keys
  __shared__ u64 skey2[KTOP];       // 8 KB   exactly sorted keys
  __shared__ float4 sbox[WIN];      // 4 KB
  __shared__ u64 smat[WIN * 4];     // 8 KB   [word][row]
  __shared__ float4 selbox[100];    // 1.6 KB
  __shared__ int s_misc[4];         // [2]=n_sel, [3]=need slow
  __shared__ int s_B, s_n;

  const u32 nHc = counters[(size_t)b * CSTRIDE];
  const u32 nLc = counters[(size_t)b * CSTRIDE + 1];
  const bool readL = (nHc < (u32)KTOP);
  const bool fb = (nHc > (u32)CAP_H) || (readL && nLc > (u32)CAP_L);

  // ---- zero hist + key arrays
  for (int i = tid; i < NBIN; i += 1024) scur[i] = 0u;
  for (int i = tid; i < KTOP; i += 1024) { skey[i] = 0ull; skey2[i] = 0ull; }
  __syncthreads();

  // ---- phase A: histogram
  if (!fb) {
    const uint2* gH = candH + (size_t)b * CAP_H;
    for (u32 i = tid; i < nHc; i += 1024) atomicAdd(&scur[score_bin(gH[i].x)], 1u);
    if (readL) {
      const uint2* gL = candL + (size_t)b * CAP_L;
      for (u32 i = tid; i < nLc; i += 1024) atomicAdd(&scur[score_bin(gL[i].x)], 1u);
    }
  } else {
    for (int P = tid; P < NPAIR; P += 1024) {
      u32 b0, b1, gi0, gi1;
      score_pair(P, b, p2, p3, p4, p5, b0, b1, gi0, gi1);
      if (b0) atomicAdd(&scur[score_bin(b0)], 1u);
      if (b1) atomicAdd(&scur[score_bin(b1)], 1u);
    }
  }
  __syncthreads();

  // ---- phase B: wave-0 shfl suffix scan over hist -> sstart, per-lane B candidate
  if (tid < 64) {
    u32 h[64];
    #pragma unroll
    for (int k = 0; k < 64; ++k) h[k] = scur[tid * 64 + k];
    u32 lsum = 0;
    #pragma unroll
    for (int k = 0; k < 64; ++k) lsum += h[k];
    u32 S = lsum;
    #pragma unroll
    for (int off = 1; off < 64; off <<= 1) {
      u32 v = (u32)__shfl_down((int)S, off, 64);
      if (tid + off < 64) S += v;
    }
    u32 c = S - lsum;                           // cnt_ge(64*tid + 64)
    int Bv = -1; u32 nv = 0;
    for (int k = 63; k >= 0; --k) {
      sstart[tid * 64 + k] = c;                 // cnt_ge(bin+1)
      c += h[k];                                // cnt_ge(bin)
      if (c <= (u32)KTOP) { Bv = tid * 64 + k; nv = c; }
    }
    scur[tid]      = (Bv < 0) ? 0xFFFFFFFFu : (u32)Bv;   // scratch (hist dead now)
    scur[64 + tid] = nv;
  }
  __syncthreads();
  if (tid == 0) {
    u32 bb = 0xFFFFFFFFu, nn = 0;
    for (int l = 0; l < 64; ++l) {
      u32 v = scur[l];
      if (v < bb) { bb = v; nn = scur[64 + l]; }
    }
    if (bb == 0xFFFFFFFFu) { s_B = 4095; s_n = KTOP; }   // unreachable
    else { s_B = max((int)bb, 1); s_n = (int)nn; }
  }
  __syncthreads();
  const int B = s_B;
  const int n = min(s_n, KTOP);

  // ---- cursors
  for (int i = tid; i < NBIN; i += 1024) scur[i] = sstart[i];
  __syncthreads();

  // ---- phase C: scatter survivors (bin >= B) into counting slots
  if (!fb) {
    const uint2* gH = candH + (size_t)b * CAP_H;
    for (u32 i = tid; i < nHc; i += 1024) {
      uint2 e = gH[i];
      int bin = score_bin(e.x);
      if (bin >= B) {
        u32 slot = atomicAdd(&scur[bin], 1u);
        if (slot < (u32)KTOP) skey[slot] = ((u64)e.x << 32) | (u32)(~e.y);
      }
    }
    if (readL) {
      const uint2* gL = candL + (size_t)b * CAP_L;
      for (u32 i = tid; i < nLc; i += 1024) {
        uint2 e = gL[i];
        int bin = score_bin(e.x);
        if (bin >= B) {
          u32 slot = atomicAdd(&scur[bin], 1u);
          if (slot < (u32)KTOP) skey[slot] = ((u64)e.x << 32) | (u32)(~e.y);
        }
      }
    }
  } else {
    for (int P = tid; P < NPAIR; P += 1024) {
      u32 b0, b1, gi0, gi1;
      score_pair(P, b, p2, p3, p4, p5, b0, b1, gi0, gi1);
      if (b0) { int bin = score_bin(b0);
        if (bin >= B) { u32 slot = atomicAdd(&scur[bin], 1u);
          if (slot < (u32)KTOP) skey[slot] = ((u64)b0 << 32) | (u32)(~gi0); } }
      if (b1) { int bin = score_bin(b1);
        if (bin >= B) { u32 slot = atomicAdd(&scur[bin], 1u);
          if (slot < (u32)KTOP) skey[slot] = ((u64)b1 << 32) | (u32)(~gi1); } }
    }
  }
  __syncthreads();

  // ---- phase D: exact rank sort within bins (barrier-free)
  for (int s = tid; s < n; s += 1024) {
    u64 k = skey[s];
    int bin = score_bin((u32)(k >> 32));
    int st = (int)sstart[bin];
    int en = (int)scur[bin];
    u32 r = 0;
    for (int j = st; j < en; ++j) r += (skey[j] > k) ? 1u : 0u;
    skey2[st + r] = k;
  }
  __syncthreads();

  const int Wn = min(n, WIN);

  // ---- phase E: decode window boxes
  if (tid < WIN) {
    sbox[tid] = (tid < Wn) ? decode_box_from_gidx(~(u32)skey2[tid], b, p2, p3, p4, p5)
                           : make_float4(0.f, 0.f, 0.f, 0.f);
  }
  __syncthreads();

  // ---- phase F: IoU bitmask matrix; row = tid&255, word = tid>>8 (broadcast reads)
  {
    int row = tid & 255, word = tid >> 8;
    u64 bits = 0;
    if (row < Wn) {
      float4 A = sbox[row];
      int j0 = word * 64;
      int je = min(64, Wn - j0);
      for (int j = 0; j < je; ++j)
        if (iou_gt(A, sbox[j0 + j])) bits |= (1ull << j);
    }
    smat[word * 256 + row] = bits;
  }
  __syncthreads();

  // ---- phase G: greedy selection on wave 0, matrix rows in registers
  if (tid < 64) {
    const int lane = tid;
    u64 m0[4], m1[4], m2[4], m3[4];
    #pragma unroll
    for (int w = 0; w < 4; ++w) {
      m0[w] = smat[w * 256 +   0 + lane];
      m1[w] = smat[w * 256 +  64 + lane];
      m2[w] = smat[w * 256 + 128 + lane];
      m3[w] = smat[w * 256 + 192 + lane];
    }
    u64 live[4];
    #pragma unroll
    for (int g2 = 0; g2 < 4; ++g2) {
      int lo = g2 * 64;
      live[g2] = (Wn >= lo + 64) ? ~0ull : (Wn > lo ? ((1ull << (Wn - lo)) - 1ull) : 0ull);
    }
    int sel = 0;
    #pragma unroll 1
    for (int w2 = 0; w2 < 4; ++w2) {
      while (live[w2] && sel < 100) {
        int j = (int)__ffsll(live[w2]) - 1;
        int p = (w2 << 6) + j;
        u64 r0, r1, r2, r3;
        if (w2 == 0)      { r0 = shfl_u64(m0[0], j); r1 = shfl_u64(m0[1], j); r2 = shfl_u64(m0[2], j); r3 = shfl_u64(m0[3], j); }
        else if (w2 == 1) { r0 = shfl_u64(m1[0], j); r1 = shfl_u64(m1[1], j); r2 = shfl_u64(m1[2], j); r3 = shfl_u64(m1[3], j); }
        else if (w2 == 2) { r0 = shfl_u64(m2[0], j); r1 = shfl_u64(m2[1], j); r2 = shfl_u64(m2[2], j); r3 = shfl_u64(m2[3], j); }
        else              { r0 = shfl_u64(m3[0], j); r1 = shfl_u64(m3[1], j); r2 = shfl_u64(m3[2], j); r3 = shfl_u64(m3[3], j); }
        live[0] &= ~r0; live[1] &= ~r1; live[2] &= ~r2; live[3] &= ~r3;
        live[w2] &= ~(1ull << j);     // self-bit (IoU(self)=1 sets it anyway)
        if (lane == 0) {
          float4 box = sbox[p];
          u64 k = skey2[p];
          float sc = __uint_as_float((u32)(k >> 32));
          selbox[sel] = box;
          float* orow = out + (size_t)b * 500 + (size_t)sel * 5;
          orow[0] = box.x; orow[1] = box.y; orow[2] = box.z; orow[3] = box.w; orow[4] = sc;
        }
        sel++;
      }
    }
    if (lane == 0) {
      s_misc[2] = sel;
      s_misc[3] = (sel < 100 && n > WIN) ? 1 : 0;
    }
  }
  __syncthreads();

  // ---- exact slow path beyond the window (statistically never taken)
  if (s_misc[3]) {
    if (tid < 64) {
      const int lane = tid;
      int sel = s_misc[2];
      for (int p = WIN; p < n && sel < 100; ++p) {
        u64 k = skey2[p];
        float4 box = decode_box_from_gidx(~(u32)k, b, p2, p3, p4, p5);
        bool hit = false;
        if (lane < sel) hit = iou_gt(selbox[lane], box);
        if (lane + 64 < sel) hit = hit || iou_gt(selbox[lane + 64], box);
        u64 anyhit = __ballot(hit);
        if (anyhit == 0ull) {
          if (lane == 0) {
            selbox[sel] = box;
            float sc = __uint_as_float((u32)(k >> 32));
            float* orow = out + (size_t)b * 500 + (size_t)sel * 5;
            orow[0] = box.x; orow[1] = box.y; orow[2] = box.z; orow[3] = box.w; orow[4] = sc;
          }
          sel++;
        }
      }
      if (lane == 0) s_misc[2] = sel;
    }
  }
  __syncthreads();

  // ---- zero-fill remaining rows
  const int nsel = s_misc[2];
  for (int i = tid; i < (100 - nsel) * 5; i += 1024)
    out[(size_t)b * 500 + (size_t)nsel * 5 + i] = 0.0f;
}

// ---------------------------------------------------------------- launch
extern "C" void kernel_launch(void* const* d_in, const int* in_sizes, int n_in,
                              void* d_out, int out_size, void* d_ws, size_t ws_size,
                              hipStream_t stream) {
  const float* p2 = (const float*)d_in[0];
  const float* p3 = (const float*)d_in[1];
  const float* p4 = (const float*)d_in[2];
  const float* p5 = (const float*)d_in[3];
  float* out = (float*)d_out;

  unsigned char* w = (unsigned char*)d_ws;
  u32*   counters = (u32*)w;
  uint2* candH    = (uint2*)(w + WS_CANDH);
  uint2* candL    = (uint2*)(w + WS_CANDL);

  hipMemsetAsync(counters, 0, 32 * CSTRIDE * sizeof(u32), stream);
  decode_kernel<<<dim3(120, 32), 256, 0, stream>>>(p2, p3, p4, p5,
                                                   counters, candH, candL);
  mega_kernel<<<32, 1024, 0, stream>>>(counters, candH, candL,
                                       p2, p3, p4, p5, out);
}